// Round 2
// baseline (290.954 us; speedup 1.0000x reference)
//
#include <hip/hip_runtime.h>

// B=2, T=2048, C=1024, H=16, D=64.
// Input dtype (fp32 vs bf16) detected at runtime from b_qkv bit patterns.
// Pipeline: detect -> convert x/bias -> transpose+convert w -> MFMA GEMM (qkv)
//           -> flash causal attention -> dtype-conditional output store.
// ws layout (bytes): flag @0 (4B); xb @1MB (8MB); wt @9MB (6MB); biasb @15MB (8KB); qkv @16MB (24MB)

#define CDIM  1024
#define C3    3072
#define HS    64

typedef __attribute__((ext_vector_type(8))) short bf16x8;
typedef __attribute__((ext_vector_type(4))) float f32x4;

__device__ __forceinline__ unsigned short f2b(float f) {
    unsigned u = __float_as_uint(f);
    unsigned r = (u + 0x7FFFu + ((u >> 16) & 1u)) >> 16;   // RNE (finite inputs)
    return (unsigned short)r;
}
__device__ __forceinline__ float b2f(unsigned short u) {
    return __uint_as_float(((unsigned)u) << 16);
}

// ------------- dtype detector: bf16 iff low-half "exponent" bits concentrated -------------
__global__ void k_detect(const unsigned* __restrict__ words, int* __restrict__ flag) {
    __shared__ int cnt;
    if (threadIdx.x == 0) cnt = 0;
    __syncthreads();
    unsigned w = words[threadIdx.x];          // 256 words = 1KB; safe in both interpretations
    unsigned e = (w >> 7) & 0xFF;             // bf16: exponent of element 2i; fp32: mantissa bits
    if (e >= 100 && e <= 135) atomicAdd(&cnt, 1);
    __syncthreads();
    if (threadIdx.x == 0) *flag = (cnt >= 200) ? 1 : 0;   // 1 = bf16, 0 = fp32
}

// ------------- convert (fp32|bf16) -> bf16, n even -------------
__global__ __launch_bounds__(256) void k_conv(const void* __restrict__ src,
                                              unsigned short* __restrict__ dst,
                                              const int* __restrict__ flag, int n) {
    int isbf = *flag;
    int i = blockIdx.x * 256 + threadIdx.x;
    int nw = n >> 1;
    if (isbf) {
        const unsigned* s = (const unsigned*)src;
        unsigned* d = (unsigned*)dst;
        for (int j = i; j < nw; j += gridDim.x * 256) d[j] = s[j];
    } else {
        const float* s = (const float*)src;
        unsigned* d = (unsigned*)dst;
        for (int j = i; j < nw; j += gridDim.x * 256) {
            float a = s[2 * j], b = s[2 * j + 1];
            d[j] = (unsigned)f2b(a) | ((unsigned)f2b(b) << 16);
        }
    }
}

// ------------- transpose+convert w [1024][3072] -> wT bf16 [3072][1024] -------------
__global__ __launch_bounds__(256) void k_tw(const void* __restrict__ w,
                                            unsigned short* __restrict__ wt,
                                            const int* __restrict__ flag) {
    __shared__ unsigned short tile[64 * 66];
    int isbf = *flag;
    int n0 = blockIdx.x * 64;
    int k0 = blockIdx.y * 64;
    int t = threadIdx.x;
    for (int i = 0; i < 16; ++i) {
        int idx = t + i * 256;
        int r = idx >> 6, c = idx & 63;
        unsigned short v;
        if (isbf) v = ((const unsigned short*)w)[(k0 + r) * C3 + n0 + c];
        else      v = f2b(((const float*)w)[(k0 + r) * C3 + n0 + c]);
        tile[r * 66 + c] = v;
    }
    __syncthreads();
    for (int i = 0; i < 16; ++i) {
        int idx = t + i * 256;
        int r = idx >> 6, c = idx & 63;
        wt[(n0 + r) * CDIM + k0 + c] = tile[c * 66 + r];
    }
}

// ------------- qkv = x @ w + bias (bf16 in/out, fp32 accum) -------------
__global__ __launch_bounds__(256) void k_gemm_qkv(const unsigned short* __restrict__ A,
                                                  const unsigned short* __restrict__ Bt,
                                                  const unsigned short* __restrict__ bias,
                                                  unsigned short* __restrict__ Cq) {
    __shared__ __align__(16) unsigned short As[128 * 32];
    __shared__ __align__(16) unsigned short Bs[128 * 32];
    int tid  = threadIdx.x;
    int lane = tid & 63, wv = tid >> 6;
    int quad = lane >> 4, l16 = lane & 15;
    int m0 = blockIdx.y * 128, n0 = blockIdx.x * 128;
    int wm = (wv >> 1) * 64, wn = (wv & 1) * 64;

    f32x4 acc[4][4] = {};

    int arow = tid >> 2;
    int acol = (tid & 3) * 8;
    const unsigned short* Ag = A  + (m0 + arow) * CDIM + acol;
    const unsigned short* Bg = Bt + (n0 + arow) * CDIM + acol;

    for (int k0 = 0; k0 < CDIM; k0 += 32) {
        uint4 a0 = *(const uint4*)(Ag);
        uint4 a1 = *(const uint4*)(Ag + 64 * CDIM);
        uint4 b0 = *(const uint4*)(Bg);
        uint4 b1 = *(const uint4*)(Bg + 64 * CDIM);
        __syncthreads();
        *(uint4*)&As[arow * 32 + acol]        = a0;
        *(uint4*)&As[(64 + arow) * 32 + acol] = a1;
        *(uint4*)&Bs[arow * 32 + acol]        = b0;
        *(uint4*)&Bs[(64 + arow) * 32 + acol] = b1;
        Ag += 32; Bg += 32;
        __syncthreads();

        bf16x8 af[4], bfr[4];
        for (int mt = 0; mt < 4; ++mt)
            af[mt] = *(const bf16x8*)&As[(wm + mt * 16 + l16) * 32 + quad * 8];
        for (int nt = 0; nt < 4; ++nt)
            bfr[nt] = *(const bf16x8*)&Bs[(wn + nt * 16 + l16) * 32 + quad * 8];
        for (int mt = 0; mt < 4; ++mt)
            for (int nt = 0; nt < 4; ++nt)
                acc[mt][nt] = __builtin_amdgcn_mfma_f32_16x16x32_bf16(af[mt], bfr[nt], acc[mt][nt], 0, 0, 0);
    }

    for (int mt = 0; mt < 4; ++mt) {
        int row = m0 + wm + mt * 16 + quad * 4;
        for (int nt = 0; nt < 4; ++nt) {
            int col = n0 + wn + nt * 16 + l16;
            float bv = b2f(bias[col]);
            for (int i = 0; i < 4; ++i) {
                float v = acc[mt][nt][i] + bv;
                Cq[(row + i) * C3 + col] = f2b(v);
            }
        }
    }
}

// ------------- causal flash attention; dtype-conditional output store -------------
#define PSTR 72
__global__ __launch_bounds__(256) void k_attn(const unsigned short* __restrict__ qkv,
                                              void* __restrict__ outv,
                                              const int* __restrict__ flag) {
    __shared__ __align__(16) unsigned short Vt[64 * PSTR];
    __shared__ __align__(16) unsigned short Pl[4][32 * PSTR];

    int isbf = *flag;
    int tid  = threadIdx.x;
    int lane = tid & 63, wv = tid >> 6;
    int quad = lane >> 4, l16 = lane & 15;
    int bh = blockIdx.y;
    int b = bh >> 4, h = bh & 15;
    int q0 = blockIdx.x * 128;
    int rowbase = b * 2048;
    int wq = q0 + wv * 32;

    bf16x8 qf[2][2];
    for (int mt = 0; mt < 2; ++mt)
        for (int kh = 0; kh < 2; ++kh)
            qf[mt][kh] = *(const bf16x8*)&qkv[(rowbase + wq + mt * 16 + l16) * C3 + h * HS + kh * 32 + quad * 8];

    f32x4 oacc[2][4] = {};
    float mrun[2][4], lrun[2][4];
    for (int mt = 0; mt < 2; ++mt)
        for (int i = 0; i < 4; ++i) { mrun[mt][i] = -1e30f; lrun[mt][i] = 0.f; }

    int kvend = q0 + 128;
    for (int kv0 = 0; kv0 < kvend; kv0 += 64) {
        __syncthreads();
        for (int i = 0; i < 16; ++i) {
            int idx = tid + i * 256;
            int d = idx & 63, r = idx >> 6;
            Vt[d * PSTR + r] = qkv[(rowbase + kv0 + r) * C3 + 2 * CDIM + h * HS + d];
        }
        __syncthreads();

        if (kv0 <= wq + 31) {
            f32x4 sacc[2][4] = {};
            for (int nt = 0; nt < 4; ++nt) {
                const unsigned short* kr = &qkv[(rowbase + kv0 + nt * 16 + l16) * C3 + CDIM + h * HS];
                bf16x8 kf0 = *(const bf16x8*)(kr + quad * 8);
                bf16x8 kf1 = *(const bf16x8*)(kr + 32 + quad * 8);
                for (int mt = 0; mt < 2; ++mt) {
                    sacc[mt][nt] = __builtin_amdgcn_mfma_f32_16x16x32_bf16(qf[mt][0], kf0, sacc[mt][nt], 0, 0, 0);
                    sacc[mt][nt] = __builtin_amdgcn_mfma_f32_16x16x32_bf16(qf[mt][1], kf1, sacc[mt][nt], 0, 0, 0);
                }
            }
            bool need_mask = (kv0 + 63 > wq);
            for (int mt = 0; mt < 2; ++mt)
                for (int nt = 0; nt < 4; ++nt)
                    for (int i = 0; i < 4; ++i) {
                        float s = sacc[mt][nt][i] * 0.125f;
                        if (need_mask) {
                            int row = wq + mt * 16 + quad * 4 + i;
                            int col = kv0 + nt * 16 + l16;
                            if (col > row) s = -1e30f;
                        }
                        sacc[mt][nt][i] = s;
                    }
            unsigned short* Pw = Pl[wv];
            for (int mt = 0; mt < 2; ++mt)
                for (int i = 0; i < 4; ++i) {
                    float rm = fmaxf(fmaxf(sacc[mt][0][i], sacc[mt][1][i]),
                                     fmaxf(sacc[mt][2][i], sacc[mt][3][i]));
                    for (int off = 1; off < 16; off <<= 1) rm = fmaxf(rm, __shfl_xor(rm, off, 16));
                    float mnew  = fmaxf(mrun[mt][i], rm);
                    float alpha = __expf(mrun[mt][i] - mnew);
                    float ps = 0.f;
                    for (int nt = 0; nt < 4; ++nt) {
                        float p = __expf(sacc[mt][nt][i] - mnew);
                        sacc[mt][nt][i] = p;
                        ps += p;
                    }
                    for (int off = 1; off < 16; off <<= 1) ps += __shfl_xor(ps, off, 16);
                    lrun[mt][i] = lrun[mt][i] * alpha + ps;
                    mrun[mt][i] = mnew;
                    for (int dt = 0; dt < 4; ++dt) oacc[mt][dt][i] *= alpha;
                }
            for (int mt = 0; mt < 2; ++mt)
                for (int nt = 0; nt < 4; ++nt)
                    for (int i = 0; i < 4; ++i)
                        Pw[(mt * 16 + quad * 4 + i) * PSTR + nt * 16 + l16] = f2b(sacc[mt][nt][i]);
            for (int kh = 0; kh < 2; ++kh) {
                bf16x8 vfk[4];
                for (int dt = 0; dt < 4; ++dt)
                    vfk[dt] = *(const bf16x8*)&Vt[(dt * 16 + l16) * PSTR + kh * 32 + quad * 8];
                for (int mt = 0; mt < 2; ++mt) {
                    bf16x8 pf = *(const bf16x8*)&Pw[(mt * 16 + l16) * PSTR + kh * 32 + quad * 8];
                    for (int dt = 0; dt < 4; ++dt)
                        oacc[mt][dt] = __builtin_amdgcn_mfma_f32_16x16x32_bf16(pf, vfk[dt], oacc[mt][dt], 0, 0, 0);
                }
            }
        }
    }

    for (int mt = 0; mt < 2; ++mt)
        for (int i = 0; i < 4; ++i) {
            float inv = 1.0f / lrun[mt][i];
            int row = rowbase + wq + mt * 16 + quad * 4 + i;
            for (int dt = 0; dt < 4; ++dt) {
                float v = oacc[mt][dt][i] * inv;
                int idx = row * CDIM + h * HS + dt * 16 + l16;
                if (isbf) ((unsigned short*)outv)[idx] = f2b(v);
                else      ((float*)outv)[idx] = v;
            }
        }
}

extern "C" void kernel_launch(void* const* d_in, const int* in_sizes, int n_in,
                              void* d_out, int out_size, void* d_ws, size_t ws_size,
                              hipStream_t stream) {
    const void* x    = d_in[0];
    const void* w    = d_in[1];
    const void* bias = d_in[2];

    char* ws = (char*)d_ws;
    int* flag             = (int*)ws;
    unsigned short* xb    = (unsigned short*)(ws + (1u  << 20));   // 8 MB
    unsigned short* wt    = (unsigned short*)(ws + (9u  << 20));   // 6 MB
    unsigned short* biasb = (unsigned short*)(ws + (15u << 20));   // 6 KB
    unsigned short* qkvb  = (unsigned short*)(ws + (16u << 20));   // 24 MB

    k_detect<<<1, 256, 0, stream>>>((const unsigned*)bias, flag);
    k_conv<<<2048, 256, 0, stream>>>(x, xb, flag, 4096 * 1024);
    k_conv<<<6, 256, 0, stream>>>(bias, biasb, flag, 3072);
    k_tw<<<dim3(48, 16), 256, 0, stream>>>(w, wt, flag);
    k_gemm_qkv<<<dim3(24, 32), 256, 0, stream>>>(xb, wt, biasb, qkvb);
    k_attn<<<dim3(16, 32), 256, 0, stream>>>(qkvb, (void*)d_out, flag);
}

// Round 4
// 190.258 us; speedup vs baseline: 1.5293x; 1.5293x over previous
//
#include <hip/hip_runtime.h>

// B=2, T=2048, C=1024, H=16, D=64. bf16 in/out (runtime dtype detect kept as safety).
// Pipeline: detect -> conv x/bias -> transpose w -> GEMM (writes Q,K to qk[t][2C],
//           V transposed to vtg[b,h,d,T]) -> balanced flash attention (S^T form).
// ws: flag@0; xb@1MB(8MB); wt@9MB(6MB); biasb@15MB; qk@16MB(16MB); vtg@32MB(8MB)

#define CDIM  1024
#define C3    3072
#define HS    64
#define TLEN  2048
#define LSTR  72          // padded LDS row stride (elements)
#define SCL   0.1803368801111204f   // (1/8) * log2(e)

typedef __attribute__((ext_vector_type(8))) short bf16x8;
typedef __attribute__((ext_vector_type(4))) float f32x4;
typedef __attribute__((ext_vector_type(4))) unsigned short u16x4;

__device__ __forceinline__ unsigned short f2b(float f) {
    unsigned u = __float_as_uint(f);
    unsigned r = (u + 0x7FFFu + ((u >> 16) & 1u)) >> 16;
    return (unsigned short)r;
}
__device__ __forceinline__ float b2f(unsigned short u) {
    return __uint_as_float(((unsigned)u) << 16);
}
__device__ __forceinline__ float fexp2(float x) {
    return __builtin_amdgcn_exp2f(x);
}
__device__ __forceinline__ void gl_lds16(const unsigned short* g, unsigned short* l) {
    __builtin_amdgcn_global_load_lds((const __attribute__((address_space(1))) void*)g,
                                     (__attribute__((address_space(3))) void*)l, 16, 0, 0);
}

__global__ void k_detect(const unsigned* __restrict__ words, int* __restrict__ flag) {
    __shared__ int cnt;
    if (threadIdx.x == 0) cnt = 0;
    __syncthreads();
    unsigned w = words[threadIdx.x];
    unsigned e = (w >> 7) & 0xFF;
    if (e >= 100 && e <= 135) atomicAdd(&cnt, 1);
    __syncthreads();
    if (threadIdx.x == 0) *flag = (cnt >= 200) ? 1 : 0;
}

__global__ __launch_bounds__(256) void k_conv(const void* __restrict__ src,
                                              unsigned short* __restrict__ dst,
                                              const int* __restrict__ flag, int n) {
    int isbf = *flag;
    int i = blockIdx.x * 256 + threadIdx.x;
    int nw = n >> 1;
    if (isbf) {
        const unsigned* s = (const unsigned*)src;
        unsigned* d = (unsigned*)dst;
        for (int j = i; j < nw; j += gridDim.x * 256) d[j] = s[j];
    } else {
        const float* s = (const float*)src;
        unsigned* d = (unsigned*)dst;
        for (int j = i; j < nw; j += gridDim.x * 256) {
            float a = s[2 * j], b = s[2 * j + 1];
            d[j] = (unsigned)f2b(a) | ((unsigned)f2b(b) << 16);
        }
    }
}

__global__ __launch_bounds__(256) void k_tw(const void* __restrict__ w,
                                            unsigned short* __restrict__ wt,
                                            const int* __restrict__ flag) {
    __shared__ unsigned short tile[64 * 66];
    int isbf = *flag;
    int n0 = blockIdx.x * 64;
    int k0 = blockIdx.y * 64;
    int t = threadIdx.x;
    for (int i = 0; i < 16; ++i) {
        int idx = t + i * 256;
        int r = idx >> 6, c = idx & 63;
        unsigned short v;
        if (isbf) v = ((const unsigned short*)w)[(k0 + r) * C3 + n0 + c];
        else      v = f2b(((const float*)w)[(k0 + r) * C3 + n0 + c]);
        tile[r * 66 + c] = v;
    }
    __syncthreads();
    for (int i = 0; i < 16; ++i) {
        int idx = t + i * 256;
        int r = idx >> 6, c = idx & 63;
        wt[(n0 + r) * CDIM + k0 + c] = tile[c * 66 + r];
    }
}

// GEMM: qkv = x @ w + bias. Q,K -> qk[t][2048]; V -> vtg[((b*16+h)*64+d)][2048] (transposed)
__global__ __launch_bounds__(256) void k_gemm_qkv(const unsigned short* __restrict__ A,
                                                  const unsigned short* __restrict__ Bt,
                                                  const unsigned short* __restrict__ bias,
                                                  unsigned short* __restrict__ qk,
                                                  unsigned short* __restrict__ vtg) {
    __shared__ __align__(16) unsigned short As[128 * 32];
    __shared__ __align__(16) unsigned short Bs[128 * 32];
    int tid  = threadIdx.x;
    int lane = tid & 63, wv = tid >> 6;
    int quad = lane >> 4, l16 = lane & 15;
    int m0 = blockIdx.y * 128, n0 = blockIdx.x * 128;
    int wm = (wv >> 1) * 64, wn = (wv & 1) * 64;

    f32x4 acc[4][4] = {};

    int arow = tid >> 2;
    int acol = (tid & 3) * 8;
    const unsigned short* Ag = A  + (m0 + arow) * CDIM + acol;
    const unsigned short* Bg = Bt + (n0 + arow) * CDIM + acol;
    unsigned short* lA0 = &As[arow * 32 + acol];
    unsigned short* lA1 = &As[(64 + arow) * 32 + acol];
    unsigned short* lB0 = &Bs[arow * 32 + acol];
    unsigned short* lB1 = &Bs[(64 + arow) * 32 + acol];

    for (int k0 = 0; k0 < CDIM; k0 += 32) {
        __syncthreads();
        gl_lds16(Ag, lA0);
        gl_lds16(Ag + 64 * CDIM, lA1);
        gl_lds16(Bg, lB0);
        gl_lds16(Bg + 64 * CDIM, lB1);
        Ag += 32; Bg += 32;
        __syncthreads();

        bf16x8 af[4], bfr[4];
        for (int mt = 0; mt < 4; ++mt)
            af[mt] = *(const bf16x8*)&As[(wm + mt * 16 + l16) * 32 + quad * 8];
        for (int nt = 0; nt < 4; ++nt)
            bfr[nt] = *(const bf16x8*)&Bs[(wn + nt * 16 + l16) * 32 + quad * 8];
        for (int mt = 0; mt < 4; ++mt)
            for (int nt = 0; nt < 4; ++nt)
                acc[mt][nt] = __builtin_amdgcn_mfma_f32_16x16x32_bf16(af[mt], bfr[nt], acc[mt][nt], 0, 0, 0);
    }

    if (n0 < 2048) {
        for (int mt = 0; mt < 4; ++mt) {
            int row = m0 + wm + mt * 16 + quad * 4;
            for (int nt = 0; nt < 4; ++nt) {
                int col = n0 + wn + nt * 16 + l16;
                float bv = b2f(bias[col]);
                for (int i = 0; i < 4; ++i)
                    qk[(row + i) * 2048 + col] = f2b(acc[mt][nt][i] + bv);
            }
        }
    } else {
        for (int mt = 0; mt < 4; ++mt) {
            int row = m0 + wm + mt * 16 + quad * 4;
            int t = row & 2047, b = row >> 11;
            for (int nt = 0; nt < 4; ++nt) {
                int col = n0 + wn + nt * 16 + l16;
                float bv = b2f(bias[col]);
                int hh = (col - 2048) >> 6, d = (col - 2048) & 63;
                u16x4 pk;
                for (int i = 0; i < 4; ++i) pk[i] = f2b(acc[mt][nt][i] + bv);
                *(u16x4*)&vtg[((b * 16 + hh) * 64 + d) * TLEN + t] = pk;
            }
        }
    }
}

// Balanced causal flash attention in S^T form.
// Block a (0..15): waves handle 16-row q-tiles j=4a+wv (seg0) and 127-4a-wv (seg1).
// Trips: seg0 = a+1, seg1 = 32-a (uniform across waves -> shared KV staging, no idle).
__global__ __launch_bounds__(256, 2) void k_attn(const unsigned short* __restrict__ qk,
                                                 const unsigned short* __restrict__ vtg,
                                                 void* __restrict__ outv,
                                                 const int* __restrict__ flag) {
    __shared__ __align__(16) unsigned short Ks[64 * LSTR];
    __shared__ __align__(16) unsigned short Vt[64 * LSTR];
    __shared__ __align__(16) unsigned short Pt[4][16 * LSTR];

    int isbf = *flag;
    int tid  = threadIdx.x;
    int lane = tid & 63, wv = tid >> 6;
    int quad = lane >> 4, l16 = lane & 15;
    int a  = blockIdx.x;
    int bh = blockIdx.y;
    int b = bh >> 4, h = bh & 15;
    int rowbase = b * TLEN;
    unsigned short* Pw = Pt[wv];

    int srow = tid >> 2;            // staging row 0..63
    int scol = (tid & 3) * 8;       // element offset (2 chunks of 8)

    for (int s = 0; s < 2; ++s) {
        int qt    = (s == 0) ? (4 * a + wv) : (127 - 4 * a - wv);
        int q0w   = qt * 16;
        int trips = (s == 0) ? (a + 1) : (32 - a);

        bf16x8 qf[2];
        for (int kh = 0; kh < 2; ++kh)
            qf[kh] = *(const bf16x8*)&qk[(rowbase + q0w + l16) * 2048 + h * HS + kh * 32 + quad * 8];

        f32x4 oacc[4] = {};
        float mrun = -1e30f, lrun = 0.f;

        for (int t = 0; t < trips; ++t) {
            int kv0 = t * 64;
            const unsigned short* kg = qk  + (rowbase + kv0 + srow) * 2048 + CDIM + h * HS + scol;
            const unsigned short* vg = vtg + (bh * 64 + srow) * TLEN + kv0 + scol;
            uint4 kc0 = *(const uint4*)kg;
            uint4 kc1 = *(const uint4*)(kg + 32);
            uint4 vc0 = *(const uint4*)vg;
            uint4 vc1 = *(const uint4*)(vg + 32);
            __syncthreads();
            *(uint4*)&Ks[srow * LSTR + scol]      = kc0;
            *(uint4*)&Ks[srow * LSTR + scol + 32] = kc1;
            *(uint4*)&Vt[srow * LSTR + scol]      = vc0;
            *(uint4*)&Vt[srow * LSTR + scol + 32] = vc1;
            __syncthreads();

            // S^T = K·Q^T  (D[kv][q])
            f32x4 sc[4];
            for (int nt = 0; nt < 4; ++nt) {
                bf16x8 kf0 = *(const bf16x8*)&Ks[(nt * 16 + l16) * LSTR + quad * 8];
                bf16x8 kf1 = *(const bf16x8*)&Ks[(nt * 16 + l16) * LSTR + 32 + quad * 8];
                f32x4 z = {};
                z = __builtin_amdgcn_mfma_f32_16x16x32_bf16(kf0, qf[0], z, 0, 0, 0);
                z = __builtin_amdgcn_mfma_f32_16x16x32_bf16(kf1, qf[1], z, 0, 0, 0);
                sc[nt] = z;
            }

            bool dm = (t == trips - 1);   // only diagonal tile needs masking
            int q = q0w + l16;
            for (int nt = 0; nt < 4; ++nt)
                for (int i = 0; i < 4; ++i) {
                    float v = sc[nt][i] * SCL;
                    if (dm) {
                        int kv = kv0 + nt * 16 + quad * 4 + i;
                        if (kv > q) v = -1e30f;
                    }
                    sc[nt][i] = v;
                }

            // column (per-q) max over kv: in-register + cross-quad butterfly
            float rm = sc[0][0];
            for (int nt = 0; nt < 4; ++nt)
                for (int i = 0; i < 4; ++i) rm = fmaxf(rm, sc[nt][i]);
            rm = fmaxf(rm, __shfl_xor(rm, 16));
            rm = fmaxf(rm, __shfl_xor(rm, 32));
            float mnew  = fmaxf(mrun, rm);
            float alpha = fexp2(mrun - mnew);
            float ps = 0.f;
            for (int nt = 0; nt < 4; ++nt)
                for (int i = 0; i < 4; ++i) {
                    float p = fexp2(sc[nt][i] - mnew);
                    sc[nt][i] = p;
                    ps += p;
                }
            ps += __shfl_xor(ps, 16);
            ps += __shfl_xor(ps, 32);
            lrun = lrun * alpha + ps;
            mrun = mnew;
            for (int dt = 0; dt < 4; ++dt)
                for (int i = 0; i < 4; ++i) oacc[dt][i] *= alpha;

            // P[q][kv] -> per-wave LDS (packed 8B writes)
            for (int nt = 0; nt < 4; ++nt) {
                u16x4 pk;
                for (int i = 0; i < 4; ++i) pk[i] = f2b(sc[nt][i]);
                *(u16x4*)&Pw[l16 * LSTR + nt * 16 + quad * 4] = pk;
            }
            // O^T += V^T · P^T
            for (int kh = 0; kh < 2; ++kh) {
                bf16x8 bp = *(const bf16x8*)&Pw[l16 * LSTR + kh * 32 + quad * 8];
                for (int dt = 0; dt < 4; ++dt) {
                    bf16x8 av = *(const bf16x8*)&Vt[(dt * 16 + l16) * LSTR + kh * 32 + quad * 8];
                    oacc[dt] = __builtin_amdgcn_mfma_f32_16x16x32_bf16(av, bp, oacc[dt], 0, 0, 0);
                }
            }
        }

        float inv = 1.0f / lrun;
        int q = q0w + l16;
        if (isbf) {
            unsigned short* out = (unsigned short*)outv;
            for (int dt = 0; dt < 4; ++dt) {
                u16x4 ov;
                for (int i = 0; i < 4; ++i) ov[i] = f2b(oacc[dt][i] * inv);
                *(u16x4*)&out[(rowbase + q) * CDIM + h * HS + dt * 16 + quad * 4] = ov;
            }
        } else {
            float* out = (float*)outv;
            for (int dt = 0; dt < 4; ++dt) {
                float4 ov;
                ov.x = oacc[dt][0] * inv; ov.y = oacc[dt][1] * inv;
                ov.z = oacc[dt][2] * inv; ov.w = oacc[dt][3] * inv;
                *(float4*)&out[(rowbase + q) * CDIM + h * HS + dt * 16 + quad * 4] = ov;
            }
        }
    }
}

extern "C" void kernel_launch(void* const* d_in, const int* in_sizes, int n_in,
                              void* d_out, int out_size, void* d_ws, size_t ws_size,
                              hipStream_t stream) {
    const void* x    = d_in[0];
    const void* w    = d_in[1];
    const void* bias = d_in[2];

    char* ws = (char*)d_ws;
    int* flag             = (int*)ws;
    unsigned short* xb    = (unsigned short*)(ws + (1u  << 20));
    unsigned short* wt    = (unsigned short*)(ws + (9u  << 20));
    unsigned short* biasb = (unsigned short*)(ws + (15u << 20));
    unsigned short* qk    = (unsigned short*)(ws + (16u << 20));
    unsigned short* vtg   = (unsigned short*)(ws + (32u << 20));

    k_detect<<<1, 256, 0, stream>>>((const unsigned*)bias, flag);
    k_conv<<<2048, 256, 0, stream>>>(x, xb, flag, 4096 * 1024);
    k_conv<<<6, 256, 0, stream>>>(bias, biasb, flag, 3072);
    k_tw<<<dim3(48, 16), 256, 0, stream>>>(w, wt, flag);
    k_gemm_qkv<<<dim3(24, 32), 256, 0, stream>>>(xb, wt, biasb, qk, vtg);
    k_attn<<<dim3(16, 32), 256, 0, stream>>>(qk, vtg, (void*)d_out, flag);
}

// Round 5
// 183.776 us; speedup vs baseline: 1.5832x; 1.0353x over previous
//
#include <hip/hip_runtime.h>
#include <hip/hip_bf16.h>

// B=2, T=2048, C=1024, H=16, D=64. bf16 in/out (runtime dtype detect kept as safety).
// detect -> conv x/bias -> transpose w -> GEMM (Q,K -> qk[t][2C], V^T -> vtg[b,h,d,T])
// -> balanced causal flash attention (S^T form, fixed-max softmax, ones-row l-sum).
// ws: flag@0; xb@1MB(8MB); wt@9MB(6MB); biasb@15MB; qk@16MB(16MB); vtg@32MB(8MB)

#define CDIM  1024
#define C3    3072
#define HS    64
#define TLEN  2048
#define KVT   128        // kv tile
#define KSTR  72         // K LDS row stride (64 el + 8)
#define VSTR  136        // V^T / P LDS row stride (128 el + 8)
#define SCL   0.1803368801111204f   // (1/8) * log2(e)

typedef __attribute__((ext_vector_type(8))) short bf16x8;
typedef __attribute__((ext_vector_type(4))) float f32x4;
typedef __attribute__((ext_vector_type(4))) unsigned short u16x4;

__device__ __forceinline__ unsigned short f2b(float f) {
    unsigned u = __float_as_uint(f);
    unsigned r = (u + 0x7FFFu + ((u >> 16) & 1u)) >> 16;
    return (unsigned short)r;
}
__device__ __forceinline__ float b2f(unsigned short u) {
    return __uint_as_float(((unsigned)u) << 16);
}
__device__ __forceinline__ float fexp2(float x) {
    return __builtin_amdgcn_exp2f(x);
}
__device__ __forceinline__ unsigned pkbf(float a, float b) {
    float2 f; f.x = a; f.y = b;
    __hip_bfloat162 h = __float22bfloat162_rn(f);
    union { __hip_bfloat162 h2; unsigned u; } c;
    c.h2 = h;
    return c.u;
}
__device__ __forceinline__ void gl_lds16(const unsigned short* g, unsigned short* l) {
    __builtin_amdgcn_global_load_lds((const __attribute__((address_space(1))) void*)g,
                                     (__attribute__((address_space(3))) void*)l, 16, 0, 0);
}

__global__ void k_detect(const unsigned* __restrict__ words, int* __restrict__ flag) {
    __shared__ int cnt;
    if (threadIdx.x == 0) cnt = 0;
    __syncthreads();
    unsigned w = words[threadIdx.x];
    unsigned e = (w >> 7) & 0xFF;
    if (e >= 100 && e <= 135) atomicAdd(&cnt, 1);
    __syncthreads();
    if (threadIdx.x == 0) *flag = (cnt >= 200) ? 1 : 0;
}

__global__ __launch_bounds__(256) void k_conv(const void* __restrict__ src,
                                              unsigned short* __restrict__ dst,
                                              const int* __restrict__ flag, int n) {
    int isbf = *flag;
    int i = blockIdx.x * 256 + threadIdx.x;
    int nw = n >> 1;
    if (isbf) {
        const unsigned* s = (const unsigned*)src;
        unsigned* d = (unsigned*)dst;
        for (int j = i; j < nw; j += gridDim.x * 256) d[j] = s[j];
    } else {
        const float* s = (const float*)src;
        unsigned* d = (unsigned*)dst;
        for (int j = i; j < nw; j += gridDim.x * 256) {
            float a = s[2 * j], b = s[2 * j + 1];
            d[j] = (unsigned)f2b(a) | ((unsigned)f2b(b) << 16);
        }
    }
}

__global__ __launch_bounds__(256) void k_tw(const void* __restrict__ w,
                                            unsigned short* __restrict__ wt,
                                            const int* __restrict__ flag) {
    __shared__ unsigned short tile[64 * 66];
    int isbf = *flag;
    int n0 = blockIdx.x * 64;
    int k0 = blockIdx.y * 64;
    int t = threadIdx.x;
    for (int i = 0; i < 16; ++i) {
        int idx = t + i * 256;
        int r = idx >> 6, c = idx & 63;
        unsigned short v;
        if (isbf) v = ((const unsigned short*)w)[(k0 + r) * C3 + n0 + c];
        else      v = f2b(((const float*)w)[(k0 + r) * C3 + n0 + c]);
        tile[r * 66 + c] = v;
    }
    __syncthreads();
    for (int i = 0; i < 16; ++i) {
        int idx = t + i * 256;
        int r = idx >> 6, c = idx & 63;
        wt[(n0 + r) * CDIM + k0 + c] = tile[c * 66 + r];
    }
}

// GEMM: qkv = x @ w + bias. Q,K -> qk[t][2048]; V -> vtg[((b*16+h)*64+d)][2048]
__global__ __launch_bounds__(256) void k_gemm_qkv(const unsigned short* __restrict__ A,
                                                  const unsigned short* __restrict__ Bt,
                                                  const unsigned short* __restrict__ bias,
                                                  unsigned short* __restrict__ qk,
                                                  unsigned short* __restrict__ vtg) {
    __shared__ __align__(16) unsigned short As[128 * 32];
    __shared__ __align__(16) unsigned short Bs[128 * 32];
    int tid  = threadIdx.x;
    int lane = tid & 63, wv = tid >> 6;
    int quad = lane >> 4, l16 = lane & 15;
    int m0 = blockIdx.y * 128, n0 = blockIdx.x * 128;
    int wm = (wv >> 1) * 64, wn = (wv & 1) * 64;

    f32x4 acc[4][4] = {};

    int arow = tid >> 2;
    int acol = (tid & 3) * 8;
    const unsigned short* Ag = A  + (m0 + arow) * CDIM + acol;
    const unsigned short* Bg = Bt + (n0 + arow) * CDIM + acol;
    unsigned short* lA0 = &As[arow * 32 + acol];
    unsigned short* lA1 = &As[(64 + arow) * 32 + acol];
    unsigned short* lB0 = &Bs[arow * 32 + acol];
    unsigned short* lB1 = &Bs[(64 + arow) * 32 + acol];

    for (int k0 = 0; k0 < CDIM; k0 += 32) {
        __syncthreads();
        gl_lds16(Ag, lA0);
        gl_lds16(Ag + 64 * CDIM, lA1);
        gl_lds16(Bg, lB0);
        gl_lds16(Bg + 64 * CDIM, lB1);
        Ag += 32; Bg += 32;
        __syncthreads();

        bf16x8 af[4], bfr[4];
        for (int mt = 0; mt < 4; ++mt)
            af[mt] = *(const bf16x8*)&As[(wm + mt * 16 + l16) * 32 + quad * 8];
        for (int nt = 0; nt < 4; ++nt)
            bfr[nt] = *(const bf16x8*)&Bs[(wn + nt * 16 + l16) * 32 + quad * 8];
        for (int mt = 0; mt < 4; ++mt)
            for (int nt = 0; nt < 4; ++nt)
                acc[mt][nt] = __builtin_amdgcn_mfma_f32_16x16x32_bf16(af[mt], bfr[nt], acc[mt][nt], 0, 0, 0);
    }

    if (n0 < 2048) {
        for (int mt = 0; mt < 4; ++mt) {
            int row = m0 + wm + mt * 16 + quad * 4;
            for (int nt = 0; nt < 4; ++nt) {
                int col = n0 + wn + nt * 16 + l16;
                float bv = b2f(bias[col]);
                for (int i = 0; i < 4; ++i)
                    qk[(row + i) * 2048 + col] = f2b(acc[mt][nt][i] + bv);
            }
        }
    } else {
        for (int mt = 0; mt < 4; ++mt) {
            int row = m0 + wm + mt * 16 + quad * 4;
            int t = row & 2047, b = row >> 11;
            for (int nt = 0; nt < 4; ++nt) {
                int col = n0 + wn + nt * 16 + l16;
                float bv = b2f(bias[col]);
                int hh = (col - 2048) >> 6, d = (col - 2048) & 63;
                u16x4 pk;
                for (int i = 0; i < 4; ++i) pk[i] = f2b(acc[mt][nt][i] + bv);
                *(u16x4*)&vtg[((b * 16 + hh) * 64 + d) * TLEN + t] = pk;
            }
        }
    }
}

// Balanced causal flash attention, S^T form, KV tile 128, fixed-max softmax.
// Block a: waves handle q-tiles 4a+wv (seg0) and 127-4a-wv (seg1); 17 trips/block.
__global__ __launch_bounds__(256, 2) void k_attn(const unsigned short* __restrict__ qk,
                                                 const unsigned short* __restrict__ vtg,
                                                 void* __restrict__ outv,
                                                 const int* __restrict__ flag) {
    __shared__ __align__(16) unsigned short Ks[128 * KSTR];
    __shared__ __align__(16) unsigned short Vt[80 * VSTR];     // rows 64..79: ones-row + zeros
    __shared__ __align__(16) unsigned short Pt[4][16 * VSTR];

    int isbf = *flag;
    int tid  = threadIdx.x;
    int lane = tid & 63, wv = tid >> 6;
    int quad = lane >> 4, l16 = lane & 15;
    int a  = blockIdx.x;
    int bh = blockIdx.y;
    int b = bh >> 4, h = bh & 15;
    int rowbase = b * TLEN;
    unsigned short* Pw = Pt[wv];

    // ones-row (d=64) + zero rows 65..79, written once
    for (int idx = tid; idx < 16 * VSTR; idx += 256) {
        int r = idx / VSTR, c = idx - r * VSTR;
        Vt[64 * VSTR + idx] = (r == 0 && c < 128) ? (unsigned short)0x3F80 : (unsigned short)0;
    }

    int sr  = tid >> 3;          // staging row 0..31
    int sc8 = (tid & 7) * 8;     // chunk offset (8 elements = 16B)

    for (int s = 0; s < 2; ++s) {
        int qt    = (s == 0) ? (4 * a + wv) : (127 - 4 * a - wv);
        int q0w   = qt * 16;
        int trips = (((s == 0) ? (4 * a) : (127 - 4 * a)) >> 3) + 1;   // uniform across waves

        bf16x8 qf[2];
        for (int kh = 0; kh < 2; ++kh)
            qf[kh] = *(const bf16x8*)&qk[(rowbase + q0w + l16) * 2048 + h * HS + kh * 32 + quad * 8];

        f32x4 oacc[5] = {};

        for (int t = 0; t < trips; ++t) {
            int kv0 = t * KVT;
            const unsigned short* kg = qk  + (rowbase + kv0 + sr) * 2048 + CDIM + h * HS + sc8;
            const unsigned short* vg = vtg + (bh * 64 + sr) * TLEN + kv0 + sc8;
            uint4 kr0 = *(const uint4*)kg;
            uint4 kr1 = *(const uint4*)(kg + 32 * 2048);
            uint4 kr2 = *(const uint4*)(kg + 64 * 2048);
            uint4 kr3 = *(const uint4*)(kg + 96 * 2048);
            uint4 vr0 = *(const uint4*)vg;
            uint4 vr1 = *(const uint4*)(vg + 64);
            uint4 vr2 = *(const uint4*)(vg + 32 * TLEN);
            uint4 vr3 = *(const uint4*)(vg + 32 * TLEN + 64);
            __syncthreads();
            *(uint4*)&Ks[sr * KSTR + sc8]         = kr0;
            *(uint4*)&Ks[(sr + 32) * KSTR + sc8]  = kr1;
            *(uint4*)&Ks[(sr + 64) * KSTR + sc8]  = kr2;
            *(uint4*)&Ks[(sr + 96) * KSTR + sc8]  = kr3;
            *(uint4*)&Vt[sr * VSTR + sc8]         = vr0;
            *(uint4*)&Vt[sr * VSTR + sc8 + 64]    = vr1;
            *(uint4*)&Vt[(sr + 32) * VSTR + sc8]      = vr2;
            *(uint4*)&Vt[(sr + 32) * VSTR + sc8 + 64] = vr3;
            __syncthreads();

            // S^T = K·Q^T  (D[kv][q], kv tile = 128)
            f32x4 sc[8];
            for (int nt = 0; nt < 8; ++nt) {
                bf16x8 kf0 = *(const bf16x8*)&Ks[(nt * 16 + l16) * KSTR + quad * 8];
                bf16x8 kf1 = *(const bf16x8*)&Ks[(nt * 16 + l16) * KSTR + 32 + quad * 8];
                f32x4 z = {};
                z = __builtin_amdgcn_mfma_f32_16x16x32_bf16(kf0, qf[0], z, 0, 0, 0);
                z = __builtin_amdgcn_mfma_f32_16x16x32_bf16(kf1, qf[1], z, 0, 0, 0);
                sc[nt] = z;
            }

            // fixed-max softmax: p = 2^(s*SCL - 12), exact after normalization
            bool dm = (t == trips - 1);
            int q = q0w + l16;
            for (int nt = 0; nt < 8; ++nt) {
                float p[4];
                for (int i = 0; i < 4; ++i) {
                    float arg = fminf(fmaf(sc[nt][i], SCL, -12.0f), 30.0f);
                    if (dm) {
                        int kv = kv0 + nt * 16 + quad * 4 + i;
                        if (kv > q) arg = -1e30f;     // exp2 -> 0
                    }
                    p[i] = fexp2(arg);
                }
                unsigned p01 = pkbf(p[0], p[1]);
                unsigned p23 = pkbf(p[2], p[3]);
                uint2 pk; pk.x = p01; pk.y = p23;
                *(uint2*)&Pw[l16 * VSTR + nt * 16 + quad * 4] = pk;
            }

            // O^T += V^T · P^T  (5th tile = ones-row -> running l-sum)
            for (int kh = 0; kh < 4; ++kh) {
                bf16x8 bp = *(const bf16x8*)&Pw[l16 * VSTR + kh * 32 + quad * 8];
                for (int dt = 0; dt < 5; ++dt) {
                    bf16x8 av = *(const bf16x8*)&Vt[(dt * 16 + l16) * VSTR + kh * 32 + quad * 8];
                    oacc[dt] = __builtin_amdgcn_mfma_f32_16x16x32_bf16(av, bp, oacc[dt], 0, 0, 0);
                }
            }
        }

        float ls  = __shfl(oacc[4][0], l16);   // l-sum for q = col l16 lives in lane l16 (quad 0)
        float inv = 1.0f / ls;
        int q = q0w + l16;
        if (isbf) {
            unsigned short* out = (unsigned short*)outv;
            for (int dt = 0; dt < 4; ++dt) {
                u16x4 ov;
                for (int i = 0; i < 4; ++i) ov[i] = f2b(oacc[dt][i] * inv);
                *(u16x4*)&out[(rowbase + q) * CDIM + h * HS + dt * 16 + quad * 4] = ov;
            }
        } else {
            float* out = (float*)outv;
            for (int dt = 0; dt < 4; ++dt) {
                float4 ov;
                ov.x = oacc[dt][0] * inv; ov.y = oacc[dt][1] * inv;
                ov.z = oacc[dt][2] * inv; ov.w = oacc[dt][3] * inv;
                *(float4*)&out[(rowbase + q) * CDIM + h * HS + dt * 16 + quad * 4] = ov;
            }
        }
    }
}

extern "C" void kernel_launch(void* const* d_in, const int* in_sizes, int n_in,
                              void* d_out, int out_size, void* d_ws, size_t ws_size,
                              hipStream_t stream) {
    const void* x    = d_in[0];
    const void* w    = d_in[1];
    const void* bias = d_in[2];

    char* ws = (char*)d_ws;
    int* flag             = (int*)ws;
    unsigned short* xb    = (unsigned short*)(ws + (1u  << 20));
    unsigned short* wt    = (unsigned short*)(ws + (9u  << 20));
    unsigned short* biasb = (unsigned short*)(ws + (15u << 20));
    unsigned short* qk    = (unsigned short*)(ws + (16u << 20));
    unsigned short* vtg   = (unsigned short*)(ws + (32u << 20));

    k_detect<<<1, 256, 0, stream>>>((const unsigned*)bias, flag);
    k_conv<<<2048, 256, 0, stream>>>(x, xb, flag, 4096 * 1024);
    k_conv<<<6, 256, 0, stream>>>(bias, biasb, flag, 3072);
    k_tw<<<dim3(48, 16), 256, 0, stream>>>(w, wt, flag);
    k_gemm_qkv<<<dim3(24, 32), 256, 0, stream>>>(xb, wt, biasb, qk, vtg);
    k_attn<<<dim3(16, 32), 256, 0, stream>>>(qk, vtg, (void*)d_out, flag);
}

// Round 6
// 158.580 us; speedup vs baseline: 1.8348x; 1.1589x over previous
//
#include <hip/hip_runtime.h>
#include <hip/hip_bf16.h>

// B=2, T=2048, C=1024, H=16, D=64. bf16 in/out (runtime dtype detect, inline per block).
// 3 kernels: k_prep (transpose w [+convert x if fp32]) -> k_gemm_qkv (BK=64, XOR-swizzled
// LDS, Q,K -> qk[t][2C], V^T -> vtg[b,h,d,T]) -> k_attn (balanced causal flash, S^T form,
// fixed-max softmax, ones-row l-sum).
// ws: xb@0(8MB); wt@8MB(6MB); qk@16MB(16MB); vtg@32MB(8MB)

#define CDIM  1024
#define C3    3072
#define HS    64
#define TLEN  2048
#define KVT   128
#define KSTR  72         // attn K LDS row stride
#define VSTR  136        // attn V^T/P LDS row stride
#define SCL   0.1803368801111204f   // (1/8) * log2(e)

typedef __attribute__((ext_vector_type(8))) short bf16x8;
typedef __attribute__((ext_vector_type(4))) float f32x4;
typedef __attribute__((ext_vector_type(4))) unsigned short u16x4;

__device__ __forceinline__ unsigned short f2b(float f) {
    unsigned u = __float_as_uint(f);
    unsigned r = (u + 0x7FFFu + ((u >> 16) & 1u)) >> 16;
    return (unsigned short)r;
}
__device__ __forceinline__ float b2f(unsigned short u) {
    return __uint_as_float(((unsigned)u) << 16);
}
__device__ __forceinline__ float fexp2(float x) {
    return __builtin_amdgcn_exp2f(x);
}
__device__ __forceinline__ unsigned pkbf(float a, float b) {
    float2 f; f.x = a; f.y = b;
    __hip_bfloat162 h = __float22bfloat162_rn(f);
    union { __hip_bfloat162 h2; unsigned u; } c;
    c.h2 = h;
    return c.u;
}
__device__ __forceinline__ void gl_lds16(const unsigned short* g, unsigned short* l) {
    __builtin_amdgcn_global_load_lds((const __attribute__((address_space(1))) void*)g,
                                     (__attribute__((address_space(3))) void*)l, 16, 0, 0);
}
// bf16 iff "exponent" bits of low halfword concentrate in the normal range.
__device__ __forceinline__ int detect_bf(const void* bias, int lane) {
    unsigned w = ((const unsigned*)bias)[lane];
    unsigned e = (w >> 7) & 0xFF;
    unsigned long long m = __ballot(e >= 100 && e <= 135);
    return __popcll(m) >= 48;
}

// prep: blocks 0..767 transpose w tile; all 2048 blocks convert an x stripe if fp32.
__global__ __launch_bounds__(256) void k_prep(const void* __restrict__ w,
                                              const void* __restrict__ x,
                                              const void* __restrict__ bias,
                                              unsigned short* __restrict__ wt,
                                              unsigned short* __restrict__ xb) {
    __shared__ unsigned short tile[64 * 66];
    int t = threadIdx.x;
    int isbf = detect_bf(bias, t & 63);
    int bid = blockIdx.x;

    if (bid < 768) {
        int n0 = (bid % 48) * 64;
        int k0 = (bid / 48) * 64;
        for (int i = 0; i < 16; ++i) {
            int idx = t + i * 256;
            int r = idx >> 6, c = idx & 63;
            unsigned short v;
            if (isbf) v = ((const unsigned short*)w)[(k0 + r) * C3 + n0 + c];
            else      v = f2b(((const float*)w)[(k0 + r) * C3 + n0 + c]);
            tile[r * 66 + c] = v;
        }
        __syncthreads();
        for (int i = 0; i < 16; ++i) {
            int idx = t + i * 256;
            int r = idx >> 6, c = idx & 63;
            wt[(n0 + r) * CDIM + k0 + c] = tile[c * 66 + r];
        }
    }
    if (!isbf) {
        const float* s = (const float*)x;
        unsigned* d = (unsigned*)xb;
        int base = bid * 1024;
        for (int j = t; j < 1024; j += 256) {
            int idx = base + j;
            float a = s[2 * idx], b = s[2 * idx + 1];
            d[idx] = (unsigned)f2b(a) | ((unsigned)f2b(b) << 16);
        }
    }
}

// GEMM: qkv = x @ w + bias. BK=64, XOR-swizzled LDS (slot kc holds chunk kc^(row&7)).
// Q,K -> qk[t][2048]; V -> vtg[((b*16+h)*64+d)][2048]
__global__ __launch_bounds__(256, 3) void k_gemm_qkv(const void* __restrict__ xraw,
                                                     const unsigned short* __restrict__ xb,
                                                     const void* __restrict__ biasraw,
                                                     const unsigned short* __restrict__ Bt,
                                                     unsigned short* __restrict__ qk,
                                                     unsigned short* __restrict__ vtg) {
    __shared__ __align__(16) unsigned short As[128 * 64];
    __shared__ __align__(16) unsigned short Bs[128 * 64];
    int tid  = threadIdx.x;
    int lane = tid & 63, wv = tid >> 6;
    int quad = lane >> 4, l16 = lane & 15;
    int isbf = detect_bf(biasraw, lane);
    const unsigned short* A = isbf ? (const unsigned short*)xraw : xb;

    int m0 = blockIdx.y * 128, n0 = blockIdx.x * 128;
    int wm = (wv >> 1) * 64, wn = (wv & 1) * 64;

    f32x4 acc[4][4] = {};

    int srow = wv * 8 + (lane >> 3);          // 0..31 (chunk j adds j*32)
    int kcg8 = (((lane & 7) ^ (lane >> 3)) * 8);
    const unsigned short* Ag = A  + (m0 + srow) * CDIM + kcg8;
    const unsigned short* Bg = Bt + (n0 + srow) * CDIM + kcg8;
    unsigned short* lA = &As[srow * 64 + (lane & 7) * 8];
    unsigned short* lB = &Bs[srow * 64 + (lane & 7) * 8];

    for (int k0 = 0; k0 < CDIM; k0 += 64) {
        __syncthreads();
        for (int j = 0; j < 4; ++j) {
            gl_lds16(Ag + j * (32 * CDIM), lA + j * (32 * 64));
            gl_lds16(Bg + j * (32 * CDIM), lB + j * (32 * 64));
        }
        Ag += 64; Bg += 64;
        __syncthreads();

        for (int kk = 0; kk < 2; ++kk) {
            int sw = (l16 & 7);
            bf16x8 af[4], bfr[4];
            for (int mt = 0; mt < 4; ++mt)
                af[mt] = *(const bf16x8*)&As[(wm + mt * 16 + l16) * 64 + (((kk * 4 + quad) ^ sw) * 8)];
            for (int nt = 0; nt < 4; ++nt)
                bfr[nt] = *(const bf16x8*)&Bs[(wn + nt * 16 + l16) * 64 + (((kk * 4 + quad) ^ sw) * 8)];
            for (int mt = 0; mt < 4; ++mt)
                for (int nt = 0; nt < 4; ++nt)
                    acc[mt][nt] = __builtin_amdgcn_mfma_f32_16x16x32_bf16(af[mt], bfr[nt], acc[mt][nt], 0, 0, 0);
        }
    }

    if (n0 < 2048) {
        for (int mt = 0; mt < 4; ++mt) {
            int row = m0 + wm + mt * 16 + quad * 4;
            for (int nt = 0; nt < 4; ++nt) {
                int col = n0 + wn + nt * 16 + l16;
                float bv = isbf ? b2f(((const unsigned short*)biasraw)[col])
                                : ((const float*)biasraw)[col];
                for (int i = 0; i < 4; ++i)
                    qk[(row + i) * 2048 + col] = f2b(acc[mt][nt][i] + bv);
            }
        }
    } else {
        for (int mt = 0; mt < 4; ++mt) {
            int row = m0 + wm + mt * 16 + quad * 4;
            int t = row & 2047, b = row >> 11;
            for (int nt = 0; nt < 4; ++nt) {
                int col = n0 + wn + nt * 16 + l16;
                float bv = isbf ? b2f(((const unsigned short*)biasraw)[col])
                                : ((const float*)biasraw)[col];
                int hh = (col - 2048) >> 6, d = (col - 2048) & 63;
                u16x4 pk;
                for (int i = 0; i < 4; ++i) pk[i] = f2b(acc[mt][nt][i] + bv);
                *(u16x4*)&vtg[((b * 16 + hh) * 64 + d) * TLEN + t] = pk;
            }
        }
    }
}

// Balanced causal flash attention, S^T form, KV tile 128, fixed-max softmax.
__global__ __launch_bounds__(256, 2) void k_attn(const unsigned short* __restrict__ qk,
                                                 const unsigned short* __restrict__ vtg,
                                                 const void* __restrict__ biasraw,
                                                 void* __restrict__ outv) {
    __shared__ __align__(16) unsigned short Ks[128 * KSTR];
    __shared__ __align__(16) unsigned short Vt[80 * VSTR];
    __shared__ __align__(16) unsigned short Pt[4][16 * VSTR];

    int tid  = threadIdx.x;
    int lane = tid & 63, wv = tid >> 6;
    int quad = lane >> 4, l16 = lane & 15;
    int isbf = detect_bf(biasraw, lane);
    int a  = blockIdx.x;
    int bh = blockIdx.y;
    int b = bh >> 4, h = bh & 15;
    int rowbase = b * TLEN;
    unsigned short* Pw = Pt[wv];

    for (int idx = tid; idx < 16 * VSTR; idx += 256) {
        int r = idx / VSTR, c = idx - r * VSTR;
        Vt[64 * VSTR + idx] = (r == 0 && c < 128) ? (unsigned short)0x3F80 : (unsigned short)0;
    }

    int sr  = tid >> 3;
    int sc8 = (tid & 7) * 8;

    for (int s = 0; s < 2; ++s) {
        int qt    = (s == 0) ? (4 * a + wv) : (127 - 4 * a - wv);
        int q0w   = qt * 16;
        int trips = (((s == 0) ? (4 * a) : (127 - 4 * a)) >> 3) + 1;

        bf16x8 qf[2];
        for (int kh = 0; kh < 2; ++kh)
            qf[kh] = *(const bf16x8*)&qk[(rowbase + q0w + l16) * 2048 + h * HS + kh * 32 + quad * 8];

        f32x4 oacc[5] = {};

        for (int t = 0; t < trips; ++t) {
            int kv0 = t * KVT;
            const unsigned short* kg = qk  + (rowbase + kv0 + sr) * 2048 + CDIM + h * HS + sc8;
            const unsigned short* vg = vtg + (bh * 64 + sr) * TLEN + kv0 + sc8;
            uint4 kr0 = *(const uint4*)kg;
            uint4 kr1 = *(const uint4*)(kg + 32 * 2048);
            uint4 kr2 = *(const uint4*)(kg + 64 * 2048);
            uint4 kr3 = *(const uint4*)(kg + 96 * 2048);
            uint4 vr0 = *(const uint4*)vg;
            uint4 vr1 = *(const uint4*)(vg + 64);
            uint4 vr2 = *(const uint4*)(vg + 32 * TLEN);
            uint4 vr3 = *(const uint4*)(vg + 32 * TLEN + 64);
            __syncthreads();
            *(uint4*)&Ks[sr * KSTR + sc8]         = kr0;
            *(uint4*)&Ks[(sr + 32) * KSTR + sc8]  = kr1;
            *(uint4*)&Ks[(sr + 64) * KSTR + sc8]  = kr2;
            *(uint4*)&Ks[(sr + 96) * KSTR + sc8]  = kr3;
            *(uint4*)&Vt[sr * VSTR + sc8]         = vr0;
            *(uint4*)&Vt[sr * VSTR + sc8 + 64]    = vr1;
            *(uint4*)&Vt[(sr + 32) * VSTR + sc8]      = vr2;
            *(uint4*)&Vt[(sr + 32) * VSTR + sc8 + 64] = vr3;
            __syncthreads();

            f32x4 sc[8];
            for (int nt = 0; nt < 8; ++nt) {
                bf16x8 kf0 = *(const bf16x8*)&Ks[(nt * 16 + l16) * KSTR + quad * 8];
                bf16x8 kf1 = *(const bf16x8*)&Ks[(nt * 16 + l16) * KSTR + 32 + quad * 8];
                f32x4 z = {};
                z = __builtin_amdgcn_mfma_f32_16x16x32_bf16(kf0, qf[0], z, 0, 0, 0);
                z = __builtin_amdgcn_mfma_f32_16x16x32_bf16(kf1, qf[1], z, 0, 0, 0);
                sc[nt] = z;
            }

            bool dm = (t == trips - 1);
            int q = q0w + l16;
            for (int nt = 0; nt < 8; ++nt) {
                float p[4];
                for (int i = 0; i < 4; ++i) {
                    float arg = fminf(fmaf(sc[nt][i], SCL, -12.0f), 30.0f);
                    if (dm) {
                        int kv = kv0 + nt * 16 + quad * 4 + i;
                        if (kv > q) arg = -1e30f;
                    }
                    p[i] = fexp2(arg);
                }
                uint2 pk;
                pk.x = pkbf(p[0], p[1]);
                pk.y = pkbf(p[2], p[3]);
                *(uint2*)&Pw[l16 * VSTR + nt * 16 + quad * 4] = pk;
            }

            for (int kh = 0; kh < 4; ++kh) {
                bf16x8 bp = *(const bf16x8*)&Pw[l16 * VSTR + kh * 32 + quad * 8];
                for (int dt = 0; dt < 5; ++dt) {
                    bf16x8 av = *(const bf16x8*)&Vt[(dt * 16 + l16) * VSTR + kh * 32 + quad * 8];
                    oacc[dt] = __builtin_amdgcn_mfma_f32_16x16x32_bf16(av, bp, oacc[dt], 0, 0, 0);
                }
            }
        }

        float ls  = __shfl(oacc[4][0], l16);
        float inv = 1.0f / ls;
        int q = q0w + l16;
        if (isbf) {
            unsigned short* out = (unsigned short*)outv;
            for (int dt = 0; dt < 4; ++dt) {
                u16x4 ov;
                for (int i = 0; i < 4; ++i) ov[i] = f2b(oacc[dt][i] * inv);
                *(u16x4*)&out[(rowbase + q) * CDIM + h * HS + dt * 16 + quad * 4] = ov;
            }
        } else {
            float* out = (float*)outv;
            for (int dt = 0; dt < 4; ++dt) {
                float4 ov;
                ov.x = oacc[dt][0] * inv; ov.y = oacc[dt][1] * inv;
                ov.z = oacc[dt][2] * inv; ov.w = oacc[dt][3] * inv;
                *(float4*)&out[(rowbase + q) * CDIM + h * HS + dt * 16 + quad * 4] = ov;
            }
        }
    }
}

extern "C" void kernel_launch(void* const* d_in, const int* in_sizes, int n_in,
                              void* d_out, int out_size, void* d_ws, size_t ws_size,
                              hipStream_t stream) {
    const void* x    = d_in[0];
    const void* w    = d_in[1];
    const void* bias = d_in[2];

    char* ws = (char*)d_ws;
    unsigned short* xb  = (unsigned short*)ws;                   // 8 MB (fp32 path only)
    unsigned short* wt  = (unsigned short*)(ws + (8u  << 20));   // 6 MB
    unsigned short* qk  = (unsigned short*)(ws + (16u << 20));   // 16 MB
    unsigned short* vtg = (unsigned short*)(ws + (32u << 20));   // 8 MB

    k_prep<<<2048, 256, 0, stream>>>(w, x, bias, wt, xb);
    k_gemm_qkv<<<dim3(24, 32), 256, 0, stream>>>(x, xb, bias, wt, qk, vtg);
    k_attn<<<dim3(16, 32), 256, 0, stream>>>(qk, vtg, bias, d_out);
}

// Round 7
// 158.341 us; speedup vs baseline: 1.8375x; 1.0015x over previous
//
#include <hip/hip_runtime.h>
#include <hip/hip_bf16.h>

// B=2, T=2048, C=1024, H=16, D=64. bf16 in/out (runtime dtype detect, inline per block).
// 3 kernels: k_prep (transpose w [+convert x if fp32]) -> k_gemm_qkv (BK=64, XOR-swizzled
// LDS, Q,K -> qk[t][2C], V^T -> vtg[b,h,d,T]) -> k_attn (balanced causal flash, S^T form,
// fixed-max softmax, ones-row l-sum; grid transposed so same-head blocks share an XCD L2).
// ws: xb@0(8MB); wt@8MB(6MB); qk@16MB(16MB); vtg@32MB(8MB)

#define CDIM  1024
#define C3    3072
#define HS    64
#define TLEN  2048
#define KVT   128
#define KSTR  72         // attn K LDS row stride
#define VSTR  136        // attn V^T/P LDS row stride
#define SCL   0.1803368801111204f   // (1/8) * log2(e)

typedef __attribute__((ext_vector_type(8))) short bf16x8;
typedef __attribute__((ext_vector_type(4))) float f32x4;
typedef __attribute__((ext_vector_type(4))) unsigned short u16x4;

__device__ __forceinline__ unsigned short f2b(float f) {
    unsigned u = __float_as_uint(f);
    unsigned r = (u + 0x7FFFu + ((u >> 16) & 1u)) >> 16;
    return (unsigned short)r;
}
__device__ __forceinline__ float b2f(unsigned short u) {
    return __uint_as_float(((unsigned)u) << 16);
}
__device__ __forceinline__ float fexp2(float x) {
    return __builtin_amdgcn_exp2f(x);
}
__device__ __forceinline__ unsigned pkbf(float a, float b) {
    float2 f; f.x = a; f.y = b;
    __hip_bfloat162 h = __float22bfloat162_rn(f);
    union { __hip_bfloat162 h2; unsigned u; } c;
    c.h2 = h;
    return c.u;
}
__device__ __forceinline__ void gl_lds16(const unsigned short* g, unsigned short* l) {
    __builtin_amdgcn_global_load_lds((const __attribute__((address_space(1))) void*)g,
                                     (__attribute__((address_space(3))) void*)l, 16, 0, 0);
}
// bf16 iff "exponent" bits of low halfword concentrate in the normal range.
__device__ __forceinline__ int detect_bf(const void* bias, int lane) {
    unsigned w = ((const unsigned*)bias)[lane];
    unsigned e = (w >> 7) & 0xFF;
    unsigned long long m = __ballot(e >= 100 && e <= 135);
    return __popcll(m) >= 48;
}

// prep: blocks 0..767 transpose w tile; all 2048 blocks convert an x stripe if fp32.
__global__ __launch_bounds__(256) void k_prep(const void* __restrict__ w,
                                              const void* __restrict__ x,
                                              const void* __restrict__ bias,
                                              unsigned short* __restrict__ wt,
                                              unsigned short* __restrict__ xb) {
    __shared__ unsigned short tile[64 * 66];
    int t = threadIdx.x;
    int isbf = detect_bf(bias, t & 63);
    int bid = blockIdx.x;

    if (bid < 768) {
        int n0 = (bid % 48) * 64;
        int k0 = (bid / 48) * 64;
        for (int i = 0; i < 16; ++i) {
            int idx = t + i * 256;
            int r = idx >> 6, c = idx & 63;
            unsigned short v;
            if (isbf) v = ((const unsigned short*)w)[(k0 + r) * C3 + n0 + c];
            else      v = f2b(((const float*)w)[(k0 + r) * C3 + n0 + c]);
            tile[r * 66 + c] = v;
        }
        __syncthreads();
        for (int i = 0; i < 16; ++i) {
            int idx = t + i * 256;
            int r = idx >> 6, c = idx & 63;
            wt[(n0 + r) * CDIM + k0 + c] = tile[c * 66 + r];
        }
    }
    if (!isbf) {
        const float* s = (const float*)x;
        unsigned* d = (unsigned*)xb;
        int base = bid * 1024;
        for (int j = t; j < 1024; j += 256) {
            int idx = base + j;
            float a = s[2 * idx], b = s[2 * idx + 1];
            d[idx] = (unsigned)f2b(a) | ((unsigned)f2b(b) << 16);
        }
    }
}

// GEMM: qkv = x @ w + bias. BK=64, XOR-swizzled LDS (slot kc holds chunk kc^(row&7)).
// Q,K -> qk[t][2048]; V -> vtg[((b*16+h)*64+d)][2048]
__global__ __launch_bounds__(256, 3) void k_gemm_qkv(const void* __restrict__ xraw,
                                                     const unsigned short* __restrict__ xb,
                                                     const void* __restrict__ biasraw,
                                                     const unsigned short* __restrict__ Bt,
                                                     unsigned short* __restrict__ qk,
                                                     unsigned short* __restrict__ vtg) {
    __shared__ __align__(16) unsigned short As[128 * 64];
    __shared__ __align__(16) unsigned short Bs[128 * 64];
    int tid  = threadIdx.x;
    int lane = tid & 63, wv = tid >> 6;
    int quad = lane >> 4, l16 = lane & 15;
    int isbf = detect_bf(biasraw, lane);
    const unsigned short* A = isbf ? (const unsigned short*)xraw : xb;

    int m0 = blockIdx.y * 128, n0 = blockIdx.x * 128;
    int wm = (wv >> 1) * 64, wn = (wv & 1) * 64;

    f32x4 acc[4][4] = {};

    int srow = wv * 8 + (lane >> 3);
    int kcg8 = (((lane & 7) ^ (lane >> 3)) * 8);
    const unsigned short* Ag = A  + (m0 + srow) * CDIM + kcg8;
    const unsigned short* Bg = Bt + (n0 + srow) * CDIM + kcg8;
    unsigned short* lA = &As[srow * 64 + (lane & 7) * 8];
    unsigned short* lB = &Bs[srow * 64 + (lane & 7) * 8];

    for (int k0 = 0; k0 < CDIM; k0 += 64) {
        __syncthreads();
        for (int j = 0; j < 4; ++j) {
            gl_lds16(Ag + j * (32 * CDIM), lA + j * (32 * 64));
            gl_lds16(Bg + j * (32 * CDIM), lB + j * (32 * 64));
        }
        Ag += 64; Bg += 64;
        __syncthreads();

        for (int kk = 0; kk < 2; ++kk) {
            int sw = (l16 & 7);
            bf16x8 af[4], bfr[4];
            for (int mt = 0; mt < 4; ++mt)
                af[mt] = *(const bf16x8*)&As[(wm + mt * 16 + l16) * 64 + (((kk * 4 + quad) ^ sw) * 8)];
            for (int nt = 0; nt < 4; ++nt)
                bfr[nt] = *(const bf16x8*)&Bs[(wn + nt * 16 + l16) * 64 + (((kk * 4 + quad) ^ sw) * 8)];
            for (int mt = 0; mt < 4; ++mt)
                for (int nt = 0; nt < 4; ++nt)
                    acc[mt][nt] = __builtin_amdgcn_mfma_f32_16x16x32_bf16(af[mt], bfr[nt], acc[mt][nt], 0, 0, 0);
        }
    }

    if (n0 < 2048) {
        for (int mt = 0; mt < 4; ++mt) {
            int row = m0 + wm + mt * 16 + quad * 4;
            for (int nt = 0; nt < 4; ++nt) {
                int col = n0 + wn + nt * 16 + l16;
                float bv = isbf ? b2f(((const unsigned short*)biasraw)[col])
                                : ((const float*)biasraw)[col];
                for (int i = 0; i < 4; ++i)
                    qk[(row + i) * 2048 + col] = f2b(acc[mt][nt][i] + bv);
            }
        }
    } else {
        for (int mt = 0; mt < 4; ++mt) {
            int row = m0 + wm + mt * 16 + quad * 4;
            int t = row & 2047, b = row >> 11;
            for (int nt = 0; nt < 4; ++nt) {
                int col = n0 + wn + nt * 16 + l16;
                float bv = isbf ? b2f(((const unsigned short*)biasraw)[col])
                                : ((const float*)biasraw)[col];
                int hh = (col - 2048) >> 6, d = (col - 2048) & 63;
                u16x4 pk;
                for (int i = 0; i < 4; ++i) pk[i] = f2b(acc[mt][nt][i] + bv);
                *(u16x4*)&vtg[((b * 16 + hh) * 64 + d) * TLEN + t] = pk;
            }
        }
    }
}

// Balanced causal flash attention, S^T form, KV tile 128, fixed-max softmax.
// Grid (32,16): bh = blockIdx.x, a = blockIdx.y -> same-bh blocks land on one XCD
// (linear id = bh + 32a, id%8 = bh%8) so each head's K/V stays in that XCD's L2.
__global__ __launch_bounds__(256, 2) void k_attn(const unsigned short* __restrict__ qk,
                                                 const unsigned short* __restrict__ vtg,
                                                 const void* __restrict__ biasraw,
                                                 void* __restrict__ outv) {
    __shared__ __align__(16) unsigned short Ks[128 * KSTR];
    __shared__ __align__(16) unsigned short Vt[80 * VSTR];
    __shared__ __align__(16) unsigned short Pt[4][16 * VSTR];

    int tid  = threadIdx.x;
    int lane = tid & 63, wv = tid >> 6;
    int quad = lane >> 4, l16 = lane & 15;
    int isbf = detect_bf(biasraw, lane);
    int bh = blockIdx.x;
    int a  = blockIdx.y;
    int b = bh >> 4, h = bh & 15;
    int rowbase = b * TLEN;
    unsigned short* Pw = Pt[wv];

    for (int idx = tid; idx < 16 * VSTR; idx += 256) {
        int r = idx / VSTR, c = idx - r * VSTR;
        Vt[64 * VSTR + idx] = (r == 0 && c < 128) ? (unsigned short)0x3F80 : (unsigned short)0;
    }

    int sr  = tid >> 3;
    int sc8 = (tid & 7) * 8;

    for (int s = 0; s < 2; ++s) {
        int qt    = (s == 0) ? (4 * a + wv) : (127 - 4 * a - wv);
        int q0w   = qt * 16;
        int trips = (((s == 0) ? (4 * a) : (127 - 4 * a)) >> 3) + 1;

        bf16x8 qf[2];
        for (int kh = 0; kh < 2; ++kh)
            qf[kh] = *(const bf16x8*)&qk[(rowbase + q0w + l16) * 2048 + h * HS + kh * 32 + quad * 8];

        f32x4 oacc[5] = {};

        for (int t = 0; t < trips; ++t) {
            int kv0 = t * KVT;
            const unsigned short* kg = qk  + (rowbase + kv0 + sr) * 2048 + CDIM + h * HS + sc8;
            const unsigned short* vg = vtg + (bh * 64 + sr) * TLEN + kv0 + sc8;
            uint4 kr0 = *(const uint4*)kg;
            uint4 kr1 = *(const uint4*)(kg + 32 * 2048);
            uint4 kr2 = *(const uint4*)(kg + 64 * 2048);
            uint4 kr3 = *(const uint4*)(kg + 96 * 2048);
            uint4 vr0 = *(const uint4*)vg;
            uint4 vr1 = *(const uint4*)(vg + 64);
            uint4 vr2 = *(const uint4*)(vg + 32 * TLEN);
            uint4 vr3 = *(const uint4*)(vg + 32 * TLEN + 64);
            __syncthreads();
            *(uint4*)&Ks[sr * KSTR + sc8]         = kr0;
            *(uint4*)&Ks[(sr + 32) * KSTR + sc8]  = kr1;
            *(uint4*)&Ks[(sr + 64) * KSTR + sc8]  = kr2;
            *(uint4*)&Ks[(sr + 96) * KSTR + sc8]  = kr3;
            *(uint4*)&Vt[sr * VSTR + sc8]         = vr0;
            *(uint4*)&Vt[sr * VSTR + sc8 + 64]    = vr1;
            *(uint4*)&Vt[(sr + 32) * VSTR + sc8]      = vr2;
            *(uint4*)&Vt[(sr + 32) * VSTR + sc8 + 64] = vr3;
            __syncthreads();

            f32x4 sc[8];
            for (int nt = 0; nt < 8; ++nt) {
                bf16x8 kf0 = *(const bf16x8*)&Ks[(nt * 16 + l16) * KSTR + quad * 8];
                bf16x8 kf1 = *(const bf16x8*)&Ks[(nt * 16 + l16) * KSTR + 32 + quad * 8];
                f32x4 z = {};
                z = __builtin_amdgcn_mfma_f32_16x16x32_bf16(kf0, qf[0], z, 0, 0, 0);
                z = __builtin_amdgcn_mfma_f32_16x16x32_bf16(kf1, qf[1], z, 0, 0, 0);
                sc[nt] = z;
            }

            bool dm = (t == trips - 1);
            int q = q0w + l16;
            for (int nt = 0; nt < 8; ++nt) {
                float p[4];
                for (int i = 0; i < 4; ++i) {
                    float arg = fminf(fmaf(sc[nt][i], SCL, -12.0f), 30.0f);
                    if (dm) {
                        int kv = kv0 + nt * 16 + quad * 4 + i;
                        if (kv > q) arg = -1e30f;
                    }
                    p[i] = fexp2(arg);
                }
                uint2 pk;
                pk.x = pkbf(p[0], p[1]);
                pk.y = pkbf(p[2], p[3]);
                *(uint2*)&Pw[l16 * VSTR + nt * 16 + quad * 4] = pk;
            }

            for (int kh = 0; kh < 4; ++kh) {
                bf16x8 bp = *(const bf16x8*)&Pw[l16 * VSTR + kh * 32 + quad * 8];
                for (int dt = 0; dt < 5; ++dt) {
                    bf16x8 av = *(const bf16x8*)&Vt[(dt * 16 + l16) * VSTR + kh * 32 + quad * 8];
                    oacc[dt] = __builtin_amdgcn_mfma_f32_16x16x32_bf16(av, bp, oacc[dt], 0, 0, 0);
                }
            }
        }

        float ls  = __shfl(oacc[4][0], l16);
        float inv = 1.0f / ls;
        int q = q0w + l16;
        if (isbf) {
            unsigned short* out = (unsigned short*)outv;
            for (int dt = 0; dt < 4; ++dt) {
                u16x4 ov;
                for (int i = 0; i < 4; ++i) ov[i] = f2b(oacc[dt][i] * inv);
                *(u16x4*)&out[(rowbase + q) * CDIM + h * HS + dt * 16 + quad * 4] = ov;
            }
        } else {
            float* out = (float*)outv;
            for (int dt = 0; dt < 4; ++dt) {
                float4 ov;
                ov.x = oacc[dt][0] * inv; ov.y = oacc[dt][1] * inv;
                ov.z = oacc[dt][2] * inv; ov.w = oacc[dt][3] * inv;
                *(float4*)&out[(rowbase + q) * CDIM + h * HS + dt * 16 + quad * 4] = ov;
            }
        }
    }
}

extern "C" void kernel_launch(void* const* d_in, const int* in_sizes, int n_in,
                              void* d_out, int out_size, void* d_ws, size_t ws_size,
                              hipStream_t stream) {
    const void* x    = d_in[0];
    const void* w    = d_in[1];
    const void* bias = d_in[2];

    char* ws = (char*)d_ws;
    unsigned short* xb  = (unsigned short*)ws;                   // 8 MB (fp32 path only)
    unsigned short* wt  = (unsigned short*)(ws + (8u  << 20));   // 6 MB
    unsigned short* qk  = (unsigned short*)(ws + (16u << 20));   // 16 MB
    unsigned short* vtg = (unsigned short*)(ws + (32u << 20));   // 8 MB

    k_prep<<<2048, 256, 0, stream>>>(w, x, bias, wt, xb);
    k_gemm_qkv<<<dim3(24, 32), 256, 0, stream>>>(x, xb, bias, wt, qk, vtg);
    k_attn<<<dim3(32, 16), 256, 0, stream>>>(qk, vtg, bias, d_out);
}